// Round 6
// baseline (3461.115 us; speedup 1.0000x reference)
//
#include <hip/hip_runtime.h>
#include <hip/hip_bf16.h>

#define NSAMP 131072
#define TA    90
#define HID   128
#define DLAT  512

// d_out layout (float elements): quant[N*512], code[N*4], recon[N*90], loss[1]
#define OFF_CODE  67108864ll
#define OFF_RECON (67108864ll + 524288ll)
#define OFF_LOSS  (67108864ll + 524288ll + 11796480ll)

// k_encvq LDS layout (floats): Act[128][65] | Wl dbuf 2x[16][128] | PZ[16][64]
#define ACT_ST 65
#define WLF    8352
#define PZF    12448
#define SHF    13472

typedef __attribute__((ext_vector_type(8))) short bf16x8;
typedef __attribute__((ext_vector_type(4))) short s16x4;
typedef __attribute__((ext_vector_type(4))) float f32x4;
typedef unsigned short ushort_t;
#define MFMA16(a, b, c) __builtin_amdgcn_mfma_f32_16x16x32_bf16(a, b, c, 0, 0, 0)

__device__ __forceinline__ ushort_t f2bf(float f) {
    unsigned u = __float_as_uint(f);
    u = (u + 0x7FFF + ((u >> 16) & 1)) >> 16;     // RNE
    return (ushort_t)u;
}

__device__ __forceinline__ float dot512(const float* __restrict__ a,
                                        const float* __restrict__ b) {
    float s = 0.f;
    for (int i = 0; i < 128; ++i) {
        float4 x = ((const float4*)a)[i], y = ((const float4*)b)[i];
        s += x.x * y.x + x.y * y.y + x.z * y.z + x.w * y.w;
    }
    return s;
}

// ---------------------------------------------------------------------------
// Strip GEMM, W staged in LDS (double-buffered): lane owns 1 sample (Act col),
// wave owns 32 outs. Per j: 8 wave-uniform ds_read_b128 (broadcast, ~free) +
// 1 conflict-free ds_read_b32 + 32 FMAs. Ascending-j fmaf chain -> results
// bit-identical to R3/R4 argmin path. Exits with a trailing barrier.
// ---------------------------------------------------------------------------
__device__ __forceinline__ void gemm_strip2(const float* __restrict__ w,
                                            int inRows,
                                            const float* __restrict__ Act,
                                            float* __restrict__ Wl,
                                            float (&acc)[32],
                                            int t, int lane, int ob) {
    const int nch = (inRows + 15) >> 4;
    const int sr = t >> 4;            // staging row 0..15
    const int sc = (t & 15) * 8;      // staging col group
    {
        int r = sr < inRows ? sr : inRows - 1;
        const float4* p = (const float4*)(w + (size_t)r * 128 + sc);
        float4 a = p[0], b = p[1];
        *(float4*)&Wl[sr * 128 + sc] = a;
        *(float4*)&Wl[sr * 128 + sc + 4] = b;
    }
    __syncthreads();
    for (int ch = 0; ch < nch; ++ch) {
        float4 na, nb;
        const bool more = (ch + 1 < nch);
        if (more) {
            int rr = (ch + 1) * 16 + sr;
            int r = rr < inRows ? rr : inRows - 1;
            const float4* p = (const float4*)(w + (size_t)r * 128 + sc);
            na = p[0]; nb = p[1];
        }
        const float* Wc = &Wl[(ch & 1) * 2048];
        const int jmax = (inRows - ch * 16) < 16 ? (inRows - ch * 16) : 16;
        for (int j = 0; j < jmax; ++j) {
            float av = Act[(ch * 16 + j) * ACT_ST + lane];
            const float4* wp = (const float4*)&Wc[j * 128 + ob];
            float4 w0 = wp[0], w1 = wp[1], w2 = wp[2], w3 = wp[3],
                   w4 = wp[4], w5 = wp[5], w6 = wp[6], w7 = wp[7];
            acc[0]  = fmaf(av, w0.x, acc[0]);  acc[1]  = fmaf(av, w0.y, acc[1]);
            acc[2]  = fmaf(av, w0.z, acc[2]);  acc[3]  = fmaf(av, w0.w, acc[3]);
            acc[4]  = fmaf(av, w1.x, acc[4]);  acc[5]  = fmaf(av, w1.y, acc[5]);
            acc[6]  = fmaf(av, w1.z, acc[6]);  acc[7]  = fmaf(av, w1.w, acc[7]);
            acc[8]  = fmaf(av, w2.x, acc[8]);  acc[9]  = fmaf(av, w2.y, acc[9]);
            acc[10] = fmaf(av, w2.z, acc[10]); acc[11] = fmaf(av, w2.w, acc[11]);
            acc[12] = fmaf(av, w3.x, acc[12]); acc[13] = fmaf(av, w3.y, acc[13]);
            acc[14] = fmaf(av, w3.z, acc[14]); acc[15] = fmaf(av, w3.w, acc[15]);
            acc[16] = fmaf(av, w4.x, acc[16]); acc[17] = fmaf(av, w4.y, acc[17]);
            acc[18] = fmaf(av, w4.z, acc[18]); acc[19] = fmaf(av, w4.w, acc[19]);
            acc[20] = fmaf(av, w5.x, acc[20]); acc[21] = fmaf(av, w5.y, acc[21]);
            acc[22] = fmaf(av, w5.z, acc[22]); acc[23] = fmaf(av, w5.w, acc[23]);
            acc[24] = fmaf(av, w6.x, acc[24]); acc[25] = fmaf(av, w6.y, acc[25]);
            acc[26] = fmaf(av, w6.z, acc[26]); acc[27] = fmaf(av, w6.w, acc[27]);
            acc[28] = fmaf(av, w7.x, acc[28]); acc[29] = fmaf(av, w7.y, acc[29]);
            acc[30] = fmaf(av, w7.z, acc[30]); acc[31] = fmaf(av, w7.w, acc[31]);
        }
        __syncthreads();
        if (more) {
            float* Wn = &Wl[((ch + 1) & 1) * 2048];
            *(float4*)&Wn[sr * 128 + sc] = na;
            *(float4*)&Wn[sr * 128 + sc + 4] = nb;
            __syncthreads();
        }
    }
}

// ---------------------------------------------------------------------------
// K0: precompute tables (fp32: P, M, t0, v, csc, cbW; bf16: Qbf, w2dT, w3dT).
// ---------------------------------------------------------------------------
__global__ void k_prep(const float* __restrict__ cb, const float* __restrict__ w3,
                       const float* __restrict__ b3, const float* __restrict__ w1d,
                       const float* __restrict__ w2d, const float* __restrict__ w3d,
                       float* __restrict__ P, float* __restrict__ M,
                       float* __restrict__ t0, float* __restrict__ v,
                       float* __restrict__ csc, float* __restrict__ cbW,
                       ushort_t* __restrict__ Qbf, ushort_t* __restrict__ w2bf,
                       ushort_t* __restrict__ w3bf) {
    int tbl = blockIdx.x >> 6;
    int gid = (blockIdx.x & 63) * 256 + threadIdx.x;   // 0..16383
    int i = gid >> 7, j = gid & 127;
    if (tbl == 0) {
        P[gid] = dot512(cb + (size_t)i * 512, cb + (size_t)j * 512);
        if (gid < 128) t0[gid] = dot512(cb + (size_t)gid * 512, b3);
        if (gid == 0) csc[0] = dot512(b3, b3);
    } else if (tbl == 1) {
        M[gid] = dot512(w3 + (size_t)i * 512, cb + (size_t)j * 512);
    } else if (tbl == 2) {
        Qbf[gid] = f2bf(dot512(w3 + (size_t)i * 512, w3 + (size_t)j * 512));
        if (gid < 128) v[gid] = dot512(w3 + (size_t)gid * 512, b3);
    } else if (tbl == 3) {
        float s = 0.f;
        for (int d = 0; d < 512; ++d) s = fmaf(cb[(size_t)i * 512 + d], w1d[d * 128 + j], s);
        cbW[gid] = s;
    } else if (tbl == 4) {
        w2bf[gid] = f2bf(w2d[j * 128 + i]);            // [o][j] = w2[j][o]
    } else {
        if (gid < 96 * 128)
            w3bf[gid] = (i < 90) ? f2bf(w3d[j * TA + i]) : (ushort_t)0;
    }
}

// ---------------------------------------------------------------------------
// K1: encoder (L1,L2) + Q-MFMA (loss only) + M-GEMM + residual-VQ argmin.
// Strip compute, LDS-staged W, conflict-free stride-65 Act. 52.6 KB -> 3/CU.
// ---------------------------------------------------------------------------
__launch_bounds__(256, 3)
__global__ void k_encvq(const float* __restrict__ X,
                        const float* __restrict__ w1, const float* __restrict__ b1,
                        const float* __restrict__ w2, const float* __restrict__ b2,
                        const float* __restrict__ Mt, const ushort_t* __restrict__ Qbf,
                        const float* __restrict__ t0g, const float* __restrict__ vg,
                        const float* __restrict__ cg, const float* __restrict__ Pg,
                        float* __restrict__ codes_out, float* __restrict__ loss_acc) {
    __shared__ __align__(16) float SH[SHF];
    float* Act = SH;
    float* Wl  = SH + WLF;
    ushort_t* h2bf = (ushort_t*)(SH + WLF);    // overlays Wl between engines
    const int t = threadIdx.x;
    const int wv = t >> 6, lane = t & 63;
    const int ob = wv * 32;
    const int row0 = blockIdx.x * 64;

    // stage X^T: j-fast (coalesced global, conflict-free LDS via stride 65)
    for (int it = 0; it < 24; ++it) {
        int idx = it * 256 + t;
        int s = idx / 96, j = idx - s * 96;
        Act[j * ACT_ST + s] = (j < 90) ? X[(size_t)(row0 + s) * TA + j] : 0.f;
    }
    __syncthreads();

    float acc[32];
    // ---- L1: 90 -> 128
#pragma unroll
    for (int i = 0; i < 32; ++i) acc[i] = 0.f;
    gemm_strip2(w1, 90, Act, Wl, acc, t, lane, ob);
#pragma unroll
    for (int i = 0; i < 32; ++i)
        Act[(ob + i) * ACT_ST + lane] = fmaxf(acc[i] + b1[ob + i], 0.f);

    // ---- L2: 128 -> 128  (chunk-0 stage barrier makes h1 visible)
#pragma unroll
    for (int i = 0; i < 32; ++i) acc[i] = 0.f;
    gemm_strip2(w2, 128, Act, Wl, acc, t, lane, ob);
    // epilogue: h2 fp32 (argmin path) + bf16 swizzled copy into h2bf (Q path)
#pragma unroll
    for (int q = 0; q < 4; ++q) {
        bf16x8 pk;
#pragma unroll
        for (int r = 0; r < 8; ++r) {
            float hv = fmaxf(acc[q * 8 + r] + b2[ob + q * 8 + r], 0.f);
            Act[(ob + q * 8 + r) * ACT_ST + lane] = hv;
            pk[r] = (short)f2bf(hv);
        }
        *(bf16x8*)&h2bf[((lane << 7) + ob + q * 8) ^ ((lane & 7) << 3)] = pk;
    }
    __syncthreads();

    // ---- Q-phase: U = Q*h2 via bf16 MFMA; znorm partials -> PZ (loss only)
    {
        const int lr = lane & 15, lg = lane >> 4;
        f32x4 qc[2][4];
#pragma unroll
        for (int m = 0; m < 2; ++m)
#pragma unroll
            for (int n = 0; n < 4; ++n) qc[m][n] = (f32x4){0.f, 0.f, 0.f, 0.f};
#pragma unroll
        for (int kt = 0; kt < 4; ++kt) {
            bf16x8 af[2], bfr[4];
#pragma unroll
            for (int m = 0; m < 2; ++m)
                af[m] = *(const bf16x8*)&Qbf[(32 * wv + 16 * m + lr) * 128 + kt * 32 + lg * 8];
#pragma unroll
            for (int n = 0; n < 4; ++n) {
                int s = 16 * n + lr;
                bfr[n] = *(const bf16x8*)&h2bf[((s << 7) + kt * 32 + lg * 8) ^ ((s & 7) << 3)];
            }
#pragma unroll
            for (int m = 0; m < 2; ++m)
#pragma unroll
                for (int n = 0; n < 4; ++n)
                    qc[m][n] = MFMA16(af[m], bfr[n], qc[m][n]);
        }
        float v2[2][4];
#pragma unroll
        for (int m = 0; m < 2; ++m)
#pragma unroll
            for (int r = 0; r < 4; ++r) v2[m][r] = 2.f * vg[32 * wv + 16 * m + lg * 4 + r];
#pragma unroll
        for (int n = 0; n < 4; ++n) {
            int s = 16 * n + lr;
            float p = 0.f;
#pragma unroll
            for (int m = 0; m < 2; ++m)
#pragma unroll
                for (int r = 0; r < 4; ++r) {
                    int o = 32 * wv + 16 * m + lg * 4 + r;
                    p = fmaf(qc[m][n][r] + v2[m][r], Act[o * ACT_ST + s], p);
                }
            SH[PZF + (wv * 4 + lg) * 64 + s] = p;
        }
    }
    __syncthreads();   // h2bf reads done before M staging overwrites Wl region

    // ---- M-scoring GEMM (fp32 — argmin-critical, bit-identical chain)
#pragma unroll
    for (int i = 0; i < 32; ++i) acc[i] = 0.f;
    gemm_strip2(Mt, 128, Act, Wl, acc, t, lane, ob);
    // dump zdot (+t0), stride 129 (overlays dead Act)
#pragma unroll
    for (int i = 0; i < 32; ++i)
        SH[lane * 129 + (ob + i)] = acc[i] + t0g[ob + i];
    __syncthreads();

    if (t < 64) {
        float znorm = cg[0];
#pragma unroll
        for (int q = 0; q < 16; ++q) znorm += SH[PZF + q * 64 + t];
        float S1 = 0.f, Sp = 0.f, msum = 0.f;
        int cs[4];
#pragma unroll
        for (int g = 0; g < 4; ++g) {
            float best = 3.4e38f; int bi = g * 32;
            float bzd = 0.f, bnrm = 0.f, bacc = 0.f;
#pragma unroll
            for (int k = 0; k < 32; ++k) {
                int c = g * 32 + k;
                float zd = SH[t * 129 + c];
                float nr = Pg[c * 128 + c];
                float a2 = 0.f;
#pragma unroll
                for (int gp = 0; gp < g; ++gp) a2 += Pg[cs[gp] * 128 + c];
                float dist = nr - 2.f * (zd - a2);
                if (dist < best) { best = dist; bi = c; bzd = zd; bnrm = nr; bacc = a2; }
            }
            cs[g] = bi;
            S1 += bzd;
            Sp += bnrm + 2.f * bacc;
            msum += (znorm - 2.f * S1 + Sp);
            codes_out[(size_t)(row0 + t) * 4 + g] = (float)(bi - g * 32);
        }
#pragma unroll
        for (int off = 32; off; off >>= 1) msum += __shfl_down(msum, off);
        if (t == 0) atomicAdd(&loss_acc[0], msum);
    }
}

// ---------------------------------------------------------------------------
// K2: quant write (fp32) + cbW-gather L1 (fp32) + bf16-MFMA decoder L2/L3.
// LDS 39.4 KB -> 4 blocks/CU.  (unchanged — R4-proven)
// ---------------------------------------------------------------------------
__launch_bounds__(256, 4)
__global__ void k_dec(const float* __restrict__ codes_f, const float* __restrict__ cb,
                      const float* __restrict__ cbW, const float* __restrict__ b1,
                      const ushort_t* __restrict__ w2bf, const float* __restrict__ b2,
                      const ushort_t* __restrict__ w3bf, const float* __restrict__ b3,
                      float* __restrict__ quant_out, float* __restrict__ recon_out) {
    __shared__ __align__(16) unsigned char SHB[39424];
    int* cods = (int*)SHB;
    ushort_t* h2bf = (ushort_t*)SHB;
    ushort_t* h1bf = (ushort_t*)(SHB + 16384);
    float* Rl = (float*)(SHB + 16384);
    const int t = threadIdx.x;
    const int st = t & 15, ct = t >> 4;
    const int s0 = st * 4, o0 = ct * 8;
    const int row0 = blockIdx.x * 64;

    cods[t] = ((t & 3) << 5) + (int)codes_f[(size_t)row0 * 4 + t];
    float rb1[8];
#pragma unroll
    for (int i = 0; i < 8; ++i) rb1[i] = b1[o0 + i];
    __syncthreads();

    for (int i = 0; i < 32; ++i) {
        int idx4 = i * 256 + t;
        int s = idx4 >> 7, d4 = (idx4 & 127) * 4;
        const int* cp = &cods[s * 4];
        float4 a = *(const float4*)&cb[(size_t)cp[0] * 512 + d4];
        float4 b = *(const float4*)&cb[(size_t)cp[1] * 512 + d4];
        float4 c = *(const float4*)&cb[(size_t)cp[2] * 512 + d4];
        float4 d = *(const float4*)&cb[(size_t)cp[3] * 512 + d4];
        float4 vv;
        vv.x = a.x + b.x + c.x + d.x;
        vv.y = a.y + b.y + c.y + d.y;
        vv.z = a.z + b.z + c.z + d.z;
        vv.w = a.w + b.w + c.w + d.w;
        *(float4*)&quant_out[(size_t)(row0 + s) * 512 + d4] = vv;
    }

    {
        float accL[8][4];
#pragma unroll
        for (int b = 0; b < 4; ++b) {
            const int* cp = &cods[(s0 + b) * 4];
            float u[8] = {0, 0, 0, 0, 0, 0, 0, 0};
#pragma unroll
            for (int g = 0; g < 4; ++g) {
                const float* r = &cbW[(size_t)cp[g] * 128 + o0];
                float4 x0 = *(const float4*)r, x1 = *(const float4*)(r + 4);
                u[0] += x0.x; u[1] += x0.y; u[2] += x0.z; u[3] += x0.w;
                u[4] += x1.x; u[5] += x1.y; u[6] += x1.z; u[7] += x1.w;
            }
#pragma unroll
            for (int a = 0; a < 8; ++a) accL[a][b] = u[a];
        }
#pragma unroll
        for (int b = 0; b < 4; ++b) {
            int s = s0 + b;
            bf16x8 pk;
#pragma unroll
            for (int a = 0; a < 8; ++a)
                pk[a] = (short)f2bf(fmaxf(accL[a][b] + rb1[a], 0.f));
            *(bf16x8*)&h1bf[((s << 7) + o0) ^ ((s & 7) << 3)] = pk;
        }
    }
    __syncthreads();

    const int wv = t >> 6, lane = t & 63, lr = lane & 15, lg = lane >> 4;

    {
        f32x4 c2[2][4];
#pragma unroll
        for (int m = 0; m < 2; ++m)
#pragma unroll
            for (int n = 0; n < 4; ++n) c2[m][n] = (f32x4){0.f, 0.f, 0.f, 0.f};
#pragma unroll
        for (int kt = 0; kt < 4; ++kt) {
            bf16x8 af[2], bfr[4];
#pragma unroll
            for (int m = 0; m < 2; ++m)
                af[m] = *(const bf16x8*)&w2bf[(32 * wv + 16 * m + lr) * 128 + kt * 32 + lg * 8];
#pragma unroll
            for (int n = 0; n < 4; ++n) {
                int s = 16 * n + lr;
                bfr[n] = *(const bf16x8*)&h1bf[((s << 7) + kt * 32 + lg * 8) ^ ((s & 7) << 3)];
            }
#pragma unroll
            for (int m = 0; m < 2; ++m)
#pragma unroll
                for (int n = 0; n < 4; ++n)
                    c2[m][n] = MFMA16(af[m], bfr[n], c2[m][n]);
        }
        float rb[2][4];
#pragma unroll
        for (int m = 0; m < 2; ++m)
#pragma unroll
            for (int r = 0; r < 4; ++r) rb[m][r] = b2[32 * wv + 16 * m + lg * 4 + r];
#pragma unroll
        for (int m = 0; m < 2; ++m)
#pragma unroll
            for (int n = 0; n < 4; ++n) {
                int s = 16 * n + lr;
                s16x4 pk;
#pragma unroll
                for (int r = 0; r < 4; ++r)
                    pk[r] = (short)f2bf(fmaxf(c2[m][n][r] + rb[m][r], 0.f));
                int ob2 = 32 * wv + 16 * m + lg * 4;
                *(s16x4*)&h2bf[((s << 7) + ob2) ^ ((s & 7) << 3)] = pk;
            }
    }
    __syncthreads();

    {
        f32x4 c3[6];
#pragma unroll
        for (int m = 0; m < 6; ++m) c3[m] = (f32x4){0.f, 0.f, 0.f, 0.f};
        const int sB = 16 * wv + lr;
#pragma unroll
        for (int kt = 0; kt < 4; ++kt) {
            bf16x8 bfr = *(const bf16x8*)&h2bf[((sB << 7) + kt * 32 + lg * 8) ^ ((sB & 7) << 3)];
#pragma unroll
            for (int mt = 0; mt < 6; ++mt) {
                bf16x8 af = *(const bf16x8*)&w3bf[(16 * mt + lr) * 128 + kt * 32 + lg * 8];
                c3[mt] = MFMA16(af, bfr, c3[mt]);
            }
        }
#pragma unroll
        for (int mt = 0; mt < 6; ++mt)
#pragma unroll
            for (int r = 0; r < 4; ++r) {
                int o = 16 * mt + lg * 4 + r;
                if (o < 90) Rl[sB * 90 + o] = c3[mt][r] + b3[o];
            }
    }
    __syncthreads();

    {
        const float4* R4v = (const float4*)Rl;
        float4* G4 = (float4*)(recon_out + (size_t)row0 * 90);
#pragma unroll
        for (int it = 0; it < 6; ++it) {
            int i4 = it * 256 + t;
            if (i4 < 1440) G4[i4] = R4v[i4];
        }
    }
}

// ---------------------------------------------------------------------------
__global__ void k_loss(const float* __restrict__ acc, float* __restrict__ out) {
    out[0] = acc[0] * (1.0f / ((float)NSAMP * (float)DLAT));
}

extern "C" void kernel_launch(void* const* d_in, const int* in_sizes, int n_in,
                              void* d_out, int out_size, void* d_ws, size_t ws_size,
                              hipStream_t stream) {
    const float* state  = (const float*)d_in[0];
    const float* enc_w1 = (const float*)d_in[1];
    const float* enc_b1 = (const float*)d_in[2];
    const float* enc_w2 = (const float*)d_in[3];
    const float* enc_b2 = (const float*)d_in[4];
    const float* enc_w3 = (const float*)d_in[5];
    const float* enc_b3 = (const float*)d_in[6];
    const float* dec_w1 = (const float*)d_in[7];
    const float* dec_b1 = (const float*)d_in[8];
    const float* dec_w2 = (const float*)d_in[9];
    const float* dec_b2 = (const float*)d_in[10];
    const float* dec_w3 = (const float*)d_in[11];
    const float* dec_b3 = (const float*)d_in[12];
    const float* cb     = (const float*)d_in[13];

    float* out = (float*)d_out;
    float* P   = out;
    float* M   = out + 16384;
    float* t0  = out + 49152;
    float* v   = out + 49280;
    float* csc = out + 49408;
    float* ws = (float*)d_ws;
    float* loss_acc = ws;
    float* cbW = ws + 256;
    ushort_t* Qbf  = (ushort_t*)(ws + 16640);
    ushort_t* w2bf = (ushort_t*)(ws + 24832);
    ushort_t* w3bf = (ushort_t*)(ws + 33024);

    hipMemsetAsync(d_ws, 0, 16, stream);
    k_prep<<<384, 256, 0, stream>>>(cb, enc_w3, enc_b3, dec_w1, dec_w2, dec_w3,
                                    P, M, t0, v, csc, cbW, Qbf, w2bf, w3bf);
    k_encvq<<<NSAMP / 64, 256, 0, stream>>>(state, enc_w1, enc_b1, enc_w2, enc_b2,
                                            M, Qbf, t0, v, csc, P,
                                            out + OFF_CODE, loss_acc);
    k_dec<<<NSAMP / 64, 256, 0, stream>>>(out + OFF_CODE, cb, cbW,
                                          dec_b1, w2bf, dec_b2, w3bf, dec_b3,
                                          out, out + OFF_RECON);
    k_loss<<<1, 1, 0, stream>>>(loss_acc, out + OFF_LOSS);
}

// Round 9
// 372.849 us; speedup vs baseline: 9.2829x; 9.2829x over previous
//
#include <hip/hip_runtime.h>
#include <hip/hip_bf16.h>

#define NSAMP 131072
#define TA    90
#define HID   128
#define DLAT  512

// d_out layout (float elements): quant[N*512], code[N*4], recon[N*90], loss[1]
#define OFF_CODE  67108864ll
#define OFF_RECON (67108864ll + 524288ll)
#define OFF_LOSS  (67108864ll + 524288ll + 11796480ll)

// k_encvq LDS (floats): Act[128][68]=8704 | Wl 2x[16][128]=4096 | PZ[4][64]=256
// ACT_ST %4==0 (float4 LDS reads need 16B alignment); 68 breaks pow2 aliasing.
#define ACT_ST 68
#define WLF    8704
#define PZF    12800
#define SHF    13056

typedef __attribute__((ext_vector_type(8))) short bf16x8;
typedef __attribute__((ext_vector_type(4))) short s16x4;
typedef __attribute__((ext_vector_type(4))) float f32x4;
typedef unsigned short ushort_t;
#define MFMA16(a, b, c) __builtin_amdgcn_mfma_f32_16x16x32_bf16(a, b, c, 0, 0, 0)

__device__ __forceinline__ ushort_t f2bf(float f) {
    unsigned u = __float_as_uint(f);
    u = (u + 0x7FFF + ((u >> 16) & 1)) >> 16;     // RNE
    return (ushort_t)u;
}

__device__ __forceinline__ float dot512(const float* __restrict__ a,
                                        const float* __restrict__ b) {
    float s = 0.f;
    for (int i = 0; i < 128; ++i) {
        float4 x = ((const float4*)a)[i], y = ((const float4*)b)[i];
        s += x.x * y.x + x.y * y.y + x.z * y.z + x.w * y.w;
    }
    return s;
}

// ---- R4-verbatim 8x4 tile FMA ----
__device__ __forceinline__ void fma_tile(float (&acc)[8][4],
                                         const float* __restrict__ wl,
                                         const float* __restrict__ al) {
    float4 av = *(const float4*)al;
    float4 w0 = *(const float4*)wl;
    float4 w1 = *(const float4*)(wl + 4);
    float aa[4] = {av.x, av.y, av.z, av.w};
    float ww[8] = {w0.x, w0.y, w0.z, w0.w, w1.x, w1.y, w1.z, w1.w};
#pragma unroll
    for (int a = 0; a < 8; ++a)
#pragma unroll
        for (int b = 0; b < 4; ++b) acc[a][b] = fmaf(ww[a], aa[b], acc[a][b]);
}

// ---- R4-verbatim double-buffered GEMM engine (2 barriers/chunk), only the
// Act stride constant changed 64 -> ACT_ST. ----
__device__ __forceinline__ void gemm_dbuf(const float* __restrict__ w, int wstride,
                                          int inRows, int nch,
                                          const float* __restrict__ Act,
                                          float* __restrict__ Wl,
                                          float (&acc)[8][4],
                                          int t, int o0, int s0) {
    const int wr = t >> 4;
    const int wc = (t & 15) * 8;
    float4 c0, c1;
    {
        int r = wr < inRows ? wr : inRows - 1;
        const float* p = w + (size_t)r * wstride + wc;
        c0 = *(const float4*)p; c1 = *(const float4*)(p + 4);
    }
    *(float4*)&Wl[wr * 128 + wc] = c0;
    *(float4*)&Wl[wr * 128 + wc + 4] = c1;
    __syncthreads();
    for (int ch = 0; ch < nch; ++ch) {
        const float* Wc = &Wl[(ch & 1) * 2048];
        const bool more = (ch + 1 < nch);
        if (more) {
            int rr = (ch + 1) * 16 + wr;
            int r = rr < inRows ? rr : inRows - 1;
            const float* p = w + (size_t)r * wstride + wc;
            c0 = *(const float4*)p; c1 = *(const float4*)(p + 4);
        }
        const float* Ab = Act + (ch * 16) * ACT_ST + s0;
#pragma unroll
        for (int j = 0; j < 16; ++j)
            fma_tile(acc, &Wc[j * 128 + o0], Ab + j * ACT_ST);
        __syncthreads();
        if (more) {
            float* Wn = &Wl[((ch + 1) & 1) * 2048];
            *(float4*)&Wn[wr * 128 + wc] = c0;
            *(float4*)&Wn[wr * 128 + wc + 4] = c1;
            __syncthreads();
        }
    }
}

// ---------------------------------------------------------------------------
// K0: precompute tables (fp32: P, M, t0, v, csc, cbW; bf16: Qbf, w2dT, w3dT).
// (R4 verbatim)
// ---------------------------------------------------------------------------
__global__ void k_prep(const float* __restrict__ cb, const float* __restrict__ w3,
                       const float* __restrict__ b3, const float* __restrict__ w1d,
                       const float* __restrict__ w2d, const float* __restrict__ w3d,
                       float* __restrict__ P, float* __restrict__ M,
                       float* __restrict__ t0, float* __restrict__ v,
                       float* __restrict__ csc, float* __restrict__ cbW,
                       ushort_t* __restrict__ Qbf, ushort_t* __restrict__ w2bf,
                       ushort_t* __restrict__ w3bf) {
    int tbl = blockIdx.x >> 6;
    int gid = (blockIdx.x & 63) * 256 + threadIdx.x;   // 0..16383
    int i = gid >> 7, j = gid & 127;
    if (tbl == 0) {
        P[gid] = dot512(cb + (size_t)i * 512, cb + (size_t)j * 512);
        if (gid < 128) t0[gid] = dot512(cb + (size_t)gid * 512, b3);
        if (gid == 0) csc[0] = dot512(b3, b3);
    } else if (tbl == 1) {
        M[gid] = dot512(w3 + (size_t)i * 512, cb + (size_t)j * 512);
    } else if (tbl == 2) {
        Qbf[gid] = f2bf(dot512(w3 + (size_t)i * 512, w3 + (size_t)j * 512));
        if (gid < 128) v[gid] = dot512(w3 + (size_t)gid * 512, b3);
    } else if (tbl == 3) {
        float s = 0.f;
        for (int d = 0; d < 512; ++d) s = fmaf(cb[(size_t)i * 512 + d], w1d[d * 128 + j], s);
        cbW[gid] = s;
    } else if (tbl == 4) {
        w2bf[gid] = f2bf(w2d[j * 128 + i]);            // [o][j] = w2[j][o]
    } else {
        if (gid < 96 * 128)
            w3bf[gid] = (i < 90) ? f2bf(w3d[j * TA + i]) : (ushort_t)0;
    }
}

// ---------------------------------------------------------------------------
// K1: R4-verbatim structure; only ACT_ST=68 layout + PZ[4][64] via shfl.
// LDS 52.2 KB -> 3 blocks/CU.
// ---------------------------------------------------------------------------
__launch_bounds__(256, 3)
__global__ void k_encvq(const float* __restrict__ X,
                        const float* __restrict__ w1, const float* __restrict__ b1,
                        const float* __restrict__ w2, const float* __restrict__ b2,
                        const float* __restrict__ Mt, const ushort_t* __restrict__ Qbf,
                        const float* __restrict__ t0g, const float* __restrict__ vg,
                        const float* __restrict__ cg, const float* __restrict__ Pg,
                        float* __restrict__ codes_out, float* __restrict__ loss_acc) {
    __shared__ __align__(16) float SH[SHF];
    float* Act = SH;
    float* Wl  = SH + WLF;
    ushort_t* h2bf = (ushort_t*)(SH + WLF);    // overlays Wl between engines
    const int t = threadIdx.x;
    const int st = t & 15, ct = t >> 4;
    const int s0 = st * 4, o0 = ct * 8;
    const int row0 = blockIdx.x * 64;

    float rb1[8], rb2[8], rt0[8];
#pragma unroll
    for (int i = 0; i < 8; ++i) {
        rb1[i] = b1[o0 + i]; rb2[i] = b2[o0 + i]; rt0[i] = t0g[o0 + i];
    }

    // stage X^T (rows 90..95 zero-padded) — R4 form, stride 68
    for (int it = 0; it < 24; ++it) {
        int idx = it * 256 + t;
        int j = idx >> 6, s = idx & 63;
        Act[j * ACT_ST + s] = (j < 90) ? X[(size_t)(row0 + s) * TA + j] : 0.f;
    }

    float acc[8][4];
#pragma unroll
    for (int a = 0; a < 8; ++a)
#pragma unroll
        for (int b = 0; b < 4; ++b) acc[a][b] = 0.f;
    gemm_dbuf(w1, HID, 90, 6, Act, Wl, acc, t, o0, s0);
#pragma unroll
    for (int a = 0; a < 8; ++a)
#pragma unroll
        for (int b = 0; b < 4; ++b)
            Act[(o0 + a) * ACT_ST + s0 + b] = fmaxf(acc[a][b] + rb1[a], 0.f);

#pragma unroll
    for (int a = 0; a < 8; ++a)
#pragma unroll
        for (int b = 0; b < 4; ++b) acc[a][b] = 0.f;
    gemm_dbuf(w2, HID, 128, 8, Act, Wl, acc, t, o0, s0);

    // L2 epilogue: h2 -> Act (fp32, argmin path) + h2bf (bf16 swz, Q path)
    {
#pragma unroll
        for (int b = 0; b < 4; ++b) {
            int s = s0 + b;
            bf16x8 pk;
#pragma unroll
            for (int a = 0; a < 8; ++a) {
                float hv = fmaxf(acc[a][b] + rb2[a], 0.f);
                Act[(o0 + a) * ACT_ST + s] = hv;
                pk[a] = (short)f2bf(hv);
            }
            *(bf16x8*)&h2bf[((s << 7) + o0) ^ ((s & 7) << 3)] = pk;
        }
    }
    __syncthreads();

    // ---- Q-phase: U = Q*h2 via bf16 MFMA; znorm partials -> PZ[4][64] (loss)
    {
        const int wv = t >> 6, lane = t & 63, lr = lane & 15, lg = lane >> 4;
        f32x4 qc[2][4];
#pragma unroll
        for (int m = 0; m < 2; ++m)
#pragma unroll
            for (int n = 0; n < 4; ++n) qc[m][n] = (f32x4){0.f, 0.f, 0.f, 0.f};
#pragma unroll
        for (int kt = 0; kt < 4; ++kt) {
            bf16x8 af[2], bfr[4];
#pragma unroll
            for (int m = 0; m < 2; ++m)
                af[m] = *(const bf16x8*)&Qbf[(32 * wv + 16 * m + lr) * 128 + kt * 32 + lg * 8];
#pragma unroll
            for (int n = 0; n < 4; ++n) {
                int s = 16 * n + lr;
                bfr[n] = *(const bf16x8*)&h2bf[((s << 7) + kt * 32 + lg * 8) ^ ((s & 7) << 3)];
            }
#pragma unroll
            for (int m = 0; m < 2; ++m)
#pragma unroll
                for (int n = 0; n < 4; ++n)
                    qc[m][n] = MFMA16(af[m], bfr[n], qc[m][n]);
        }
        float v2[2][4];
#pragma unroll
        for (int m = 0; m < 2; ++m)
#pragma unroll
            for (int r = 0; r < 4; ++r) v2[m][r] = 2.f * vg[32 * wv + 16 * m + lg * 4 + r];
#pragma unroll
        for (int n = 0; n < 4; ++n) {
            int s = 16 * n + lr;
            float p = 0.f;
#pragma unroll
            for (int m = 0; m < 2; ++m)
#pragma unroll
                for (int r = 0; r < 4; ++r) {
                    int o = 32 * wv + 16 * m + lg * 4 + r;
                    p = fmaf(qc[m][n][r] + v2[m][r], Act[o * ACT_ST + s], p);
                }
            p += __shfl_xor(p, 16);
            p += __shfl_xor(p, 32);
            if (lg == 0) SH[PZF + wv * 64 + s] = p;
        }
    }
    __syncthreads();   // h2bf reads done before M staging reuses Wl

    // ---- M-scoring GEMM (fp32 — argmin-critical, R4-identical chains)
#pragma unroll
    for (int a = 0; a < 8; ++a)
#pragma unroll
        for (int b = 0; b < 4; ++b) acc[a][b] = 0.f;
    gemm_dbuf(Mt, 128, 128, 8, Act, Wl, acc, t, o0, s0);

    // dump zdot (+t0) over Act, stride 129 (max 8254 < 8704)
#pragma unroll
    for (int a = 0; a < 8; ++a)
#pragma unroll
        for (int b = 0; b < 4; ++b)
            SH[(s0 + b) * 129 + (o0 + a)] = acc[a][b] + rt0[a];
    __syncthreads();

    if (t < 64) {
        float znorm = cg[0] + SH[PZF + t] + SH[PZF + 64 + t]
                    + SH[PZF + 128 + t] + SH[PZF + 192 + t];
        float S1 = 0.f, Sp = 0.f, msum = 0.f;
        int cs[4];
#pragma unroll
        for (int g = 0; g < 4; ++g) {
            float best = 3.4e38f; int bi = g * 32;
            float bzd = 0.f, bnrm = 0.f, bacc = 0.f;
#pragma unroll
            for (int k = 0; k < 32; ++k) {
                int c = g * 32 + k;
                float zd = SH[t * 129 + c];
                float nr = Pg[c * 128 + c];
                float a2 = 0.f;
#pragma unroll
                for (int gp = 0; gp < g; ++gp) a2 += Pg[cs[gp] * 128 + c];
                float dist = nr - 2.f * (zd - a2);
                if (dist < best) { best = dist; bi = c; bzd = zd; bnrm = nr; bacc = a2; }
            }
            cs[g] = bi;
            S1 += bzd;
            Sp += bnrm + 2.f * bacc;
            msum += (znorm - 2.f * S1 + Sp);
            codes_out[(size_t)(row0 + t) * 4 + g] = (float)(bi - g * 32);
        }
#pragma unroll
        for (int off = 32; off; off >>= 1) msum += __shfl_down(msum, off);
        if (t == 0) atomicAdd(&loss_acc[0], msum);
    }
}

// ---------------------------------------------------------------------------
// K2: quant write (fp32) + cbW-gather L1 (fp32) + bf16-MFMA decoder L2/L3.
// (R4 verbatim)
// ---------------------------------------------------------------------------
__launch_bounds__(256, 4)
__global__ void k_dec(const float* __restrict__ codes_f, const float* __restrict__ cb,
                      const float* __restrict__ cbW, const float* __restrict__ b1,
                      const ushort_t* __restrict__ w2bf, const float* __restrict__ b2,
                      const ushort_t* __restrict__ w3bf, const float* __restrict__ b3,
                      float* __restrict__ quant_out, float* __restrict__ recon_out) {
    __shared__ __align__(16) unsigned char SHB[39424];
    int* cods = (int*)SHB;
    ushort_t* h2bf = (ushort_t*)SHB;
    ushort_t* h1bf = (ushort_t*)(SHB + 16384);
    float* Rl = (float*)(SHB + 16384);
    const int t = threadIdx.x;
    const int st = t & 15, ct = t >> 4;
    const int s0 = st * 4, o0 = ct * 8;
    const int row0 = blockIdx.x * 64;

    cods[t] = ((t & 3) << 5) + (int)codes_f[(size_t)row0 * 4 + t];
    float rb1[8];
#pragma unroll
    for (int i = 0; i < 8; ++i) rb1[i] = b1[o0 + i];
    __syncthreads();

    for (int i = 0; i < 32; ++i) {
        int idx4 = i * 256 + t;
        int s = idx4 >> 7, d4 = (idx4 & 127) * 4;
        const int* cp = &cods[s * 4];
        float4 a = *(const float4*)&cb[(size_t)cp[0] * 512 + d4];
        float4 b = *(const float4*)&cb[(size_t)cp[1] * 512 + d4];
        float4 c = *(const float4*)&cb[(size_t)cp[2] * 512 + d4];
        float4 d = *(const float4*)&cb[(size_t)cp[3] * 512 + d4];
        float4 vv;
        vv.x = a.x + b.x + c.x + d.x;
        vv.y = a.y + b.y + c.y + d.y;
        vv.z = a.z + b.z + c.z + d.z;
        vv.w = a.w + b.w + c.w + d.w;
        *(float4*)&quant_out[(size_t)(row0 + s) * 512 + d4] = vv;
    }

    {
        float accL[8][4];
#pragma unroll
        for (int b = 0; b < 4; ++b) {
            const int* cp = &cods[(s0 + b) * 4];
            float u[8] = {0, 0, 0, 0, 0, 0, 0, 0};
#pragma unroll
            for (int g = 0; g < 4; ++g) {
                const float* r = &cbW[(size_t)cp[g] * 128 + o0];
                float4 x0 = *(const float4*)r, x1 = *(const float4*)(r + 4);
                u[0] += x0.x; u[1] += x0.y; u[2] += x0.z; u[3] += x0.w;
                u[4] += x1.x; u[5] += x1.y; u[6] += x1.z; u[7] += x1.w;
            }
#pragma unroll
            for (int a = 0; a < 8; ++a) accL[a][b] = u[a];
        }
#pragma unroll
        for (int b = 0; b < 4; ++b) {
            int s = s0 + b;
            bf16x8 pk;
#pragma unroll
            for (int a = 0; a < 8; ++a)
                pk[a] = (short)f2bf(fmaxf(accL[a][b] + rb1[a], 0.f));
            *(bf16x8*)&h1bf[((s << 7) + o0) ^ ((s & 7) << 3)] = pk;
        }
    }
    __syncthreads();

    const int wv = t >> 6, lane = t & 63, lr = lane & 15, lg = lane >> 4;

    {
        f32x4 c2[2][4];
#pragma unroll
        for (int m = 0; m < 2; ++m)
#pragma unroll
            for (int n = 0; n < 4; ++n) c2[m][n] = (f32x4){0.f, 0.f, 0.f, 0.f};
#pragma unroll
        for (int kt = 0; kt < 4; ++kt) {
            bf16x8 af[2], bfr[4];
#pragma unroll
            for (int m = 0; m < 2; ++m)
                af[m] = *(const bf16x8*)&w2bf[(32 * wv + 16 * m + lr) * 128 + kt * 32 + lg * 8];
#pragma unroll
            for (int n = 0; n < 4; ++n) {
                int s = 16 * n + lr;
                bfr[n] = *(const bf16x8*)&h1bf[((s << 7) + kt * 32 + lg * 8) ^ ((s & 7) << 3)];
            }
#pragma unroll
            for (int m = 0; m < 2; ++m)
#pragma unroll
                for (int n = 0; n < 4; ++n)
                    c2[m][n] = MFMA16(af[m], bfr[n], c2[m][n]);
        }
        float rb[2][4];
#pragma unroll
        for (int m = 0; m < 2; ++m)
#pragma unroll
            for (int r = 0; r < 4; ++r) rb[m][r] = b2[32 * wv + 16 * m + lg * 4 + r];
#pragma unroll
        for (int m = 0; m < 2; ++m)
#pragma unroll
            for (int n = 0; n < 4; ++n) {
                int s = 16 * n + lr;
                s16x4 pk;
#pragma unroll
                for (int r = 0; r < 4; ++r)
                    pk[r] = (short)f2bf(fmaxf(c2[m][n][r] + rb[m][r], 0.f));
                int ob2 = 32 * wv + 16 * m + lg * 4;
                *(s16x4*)&h2bf[((s << 7) + ob2) ^ ((s & 7) << 3)] = pk;
            }
    }
    __syncthreads();

    {
        f32x4 c3[6];
#pragma unroll
        for (int m = 0; m < 6; ++m) c3[m] = (f32x4){0.f, 0.f, 0.f, 0.f};
        const int sB = 16 * wv + lr;
#pragma unroll
        for (int kt = 0; kt < 4; ++kt) {
            bf16x8 bfr = *(const bf16x8*)&h2bf[((sB << 7) + kt * 32 + lg * 8) ^ ((sB & 7) << 3)];
#pragma unroll
            for (int mt = 0; mt < 6; ++mt) {
                bf16x8 af = *(const bf16x8*)&w3bf[(16 * mt + lr) * 128 + kt * 32 + lg * 8];
                c3[mt] = MFMA16(af, bfr, c3[mt]);
            }
        }
#pragma unroll
        for (int mt = 0; mt < 6; ++mt)
#pragma unroll
            for (int r = 0; r < 4; ++r) {
                int o = 16 * mt + lg * 4 + r;
                if (o < 90) Rl[sB * 90 + o] = c3[mt][r] + b3[o];
            }
    }
    __syncthreads();

    {
        const float4* R4v = (const float4*)Rl;
        float4* G4 = (float4*)(recon_out + (size_t)row0 * 90);
#pragma unroll
        for (int it = 0; it < 6; ++it) {
            int i4 = it * 256 + t;
            if (i4 < 1440) G4[i4] = R4v[i4];
        }
    }
}

// ---------------------------------------------------------------------------
__global__ void k_loss(const float* __restrict__ acc, float* __restrict__ out) {
    out[0] = acc[0] * (1.0f / ((float)NSAMP * (float)DLAT));
}

extern "C" void kernel_launch(void* const* d_in, const int* in_sizes, int n_in,
                              void* d_out, int out_size, void* d_ws, size_t ws_size,
                              hipStream_t stream) {
    const float* state  = (const float*)d_in[0];
    const float* enc_w1 = (const float*)d_in[1];
    const float* enc_b1 = (const float*)d_in[2];
    const float* enc_w2 = (const float*)d_in[3];
    const float* enc_b2 = (const float*)d_in[4];
    const float* enc_w3 = (const float*)d_in[5];
    const float* enc_b3 = (const float*)d_in[6];
    const float* dec_w1 = (const float*)d_in[7];
    const float* dec_b1 = (const float*)d_in[8];
    const float* dec_w2 = (const float*)d_in[9];
    const float* dec_b2 = (const float*)d_in[10];
    const float* dec_w3 = (const float*)d_in[11];
    const float* dec_b3 = (const float*)d_in[12];
    const float* cb     = (const float*)d_in[13];

    float* out = (float*)d_out;
    float* P   = out;
    float* M   = out + 16384;
    float* t0  = out + 49152;
    float* v   = out + 49280;
    float* csc = out + 49408;
    float* ws = (float*)d_ws;
    float* loss_acc = ws;
    float* cbW = ws + 256;
    ushort_t* Qbf  = (ushort_t*)(ws + 16640);
    ushort_t* w2bf = (ushort_t*)(ws + 24832);
    ushort_t* w3bf = (ushort_t*)(ws + 33024);

    hipMemsetAsync(d_ws, 0, 16, stream);
    k_prep<<<384, 256, 0, stream>>>(cb, enc_w3, enc_b3, dec_w1, dec_w2, dec_w3,
                                    P, M, t0, v, csc, cbW, Qbf, w2bf, w3bf);
    k_encvq<<<NSAMP / 64, 256, 0, stream>>>(state, enc_w1, enc_b1, enc_w2, enc_b2,
                                            M, Qbf, t0, v, csc, P,
                                            out + OFF_CODE, loss_acc);
    k_dec<<<NSAMP / 64, 256, 0, stream>>>(out + OFF_CODE, cb, cbW,
                                          dec_b1, w2bf, dec_b2, w3bf, dec_b3,
                                          out, out + OFF_RECON);
    k_loss<<<1, 1, 0, stream>>>(loss_acc, out + OFF_LOSS);
}